// Round 9
// baseline (304.800 us; speedup 1.0000x reference)
//
#include <hip/hip_runtime.h>

#define N_NODES 100000
#define N_EDGES 1600000
#define F_IN 128
#define F_OUT 64
#define BN_EPS 1e-5f

#define NPART 2            // node partitions (p = d >= PSIZE)
#define NCHUNK 128         // edge chunks
#define PSIZE 50000        // nodes per partition
#define CHUNK_E 12500      // edges per chunk

#define SCAN_NB 98         // ceil(100000/1024) scan blocks

// ---------------- workspace layout (4-byte elements) ----------------
// s32    : [0,        1600000)   edge sources, int32
// d32    : [1600000,  3200000)   edge dests, int32
// partial: [3200000,  6400000)   byte per (chunk, node): deg-nibble|cnt-nibble,
//                                then u8 cnt-prefix; hb (bf16 h') aliases after place
// buck   : [6400000,  9600000)   int2 {src, ew-bits} per edge
// dinv   : [9600000,  9700000)
// sums   : [9700000,  9700128)
// off    : [9800128,  9900128)   block-local exclusive prefix (add bsum[n>>10])
// bsum   : [9900128,  9900256)
// rank   : first 1.6 MB of d_out (u8/edge; consumed by place before aggregate writes)

typedef __attribute__((ext_vector_type(8))) short bf16x8;
typedef __attribute__((ext_vector_type(4))) float f32x4;

__device__ __forceinline__ unsigned short f2bf(float x) {
    unsigned u = __float_as_uint(x);
    u += 0x7fffu + ((u >> 16) & 1u);   // RTNE
    return (unsigned short)(u >> 16);
}
__device__ __forceinline__ float bfl(unsigned short v) {
    return __int_as_float(((int)v) << 16);
}

// ei -> int32 SoA, inline int64-vs-int32 detection (64-sample ballot).
__global__ __launch_bounds__(256) void convert_kernel(const void* __restrict__ ei,
                                                      int* __restrict__ s32,
                                                      int* __restrict__ d32) {
    const long long* q = (const long long*)ei;
    long long probe = q[threadIdx.x & 63];
    bool bad = (probe < 0 || probe >= N_NODES);
    int is64 = (__ballot(bad) == 0ULL);

    int i = blockIdx.x * 256 + threadIdx.x;   // int4 index
    if (i >= N_EDGES / 4) return;
    int4 s, d;
    if (is64) {
        longlong2 a = *(const longlong2*)&q[i * 4];
        longlong2 b = *(const longlong2*)&q[i * 4 + 2];
        s = make_int4((int)a.x, (int)a.y, (int)b.x, (int)b.y);
        longlong2 c = *(const longlong2*)&q[N_EDGES + i * 4];
        longlong2 e = *(const longlong2*)&q[N_EDGES + i * 4 + 2];
        d = make_int4((int)c.x, (int)c.y, (int)e.x, (int)e.y);
    } else {
        s = ((const int4*)ei)[i];
        d = ((const int4*)ei)[N_EDGES / 4 + i];
    }
    ((int4*)s32)[i] = s;
    ((int4*)d32)[i] = d;
}

// Block (p,b): nibble-packed histogram of chunk b for partition p.
// LDS byte per node: deg (low nibble) | cnt (high nibble); cnt atomicAdd return
// value = within-(chunk,dst) rank -> rank[].
__global__ __launch_bounds__(512) void count_kernel(const int* __restrict__ s32,
                                                    const int* __restrict__ d32,
                                                    unsigned* __restrict__ partial32,
                                                    unsigned char* __restrict__ rank) {
    __shared__ unsigned bins[PSIZE / 4];   // 50 KB
    const int tid = threadIdx.x;
    const int p = blockIdx.x % NPART;
    const int b = blockIdx.x / NPART;
    const int p0 = p * PSIZE;
    for (int i = tid; i < PSIZE / 4; i += 512) bins[i] = 0u;
    __syncthreads();
    const int4* sp = (const int4*)(s32 + b * CHUNK_E);
    const int4* dp = (const int4*)(d32 + b * CHUNK_E);
    const int e0 = b * CHUNK_E;
    for (int i = tid; i < CHUNK_E / 4; i += 512) {
        int4 s = sp[i];
        int4 d = dp[i];
        int e = e0 + i * 4;
#define C1(sk, dk, kk) { \
        unsigned si = (unsigned)((sk) - p0); \
        if (si < PSIZE) atomicAdd(&bins[si >> 2], 1u << ((si & 3) * 8)); \
        unsigned dd = (unsigned)((dk) - p0); \
        if ((unsigned)(sk) < N_NODES && dd < PSIZE) { \
            unsigned sh = (dd & 3) * 8 + 4; \
            unsigned old = atomicAdd(&bins[dd >> 2], 16u << ((dd & 3) * 8)); \
            rank[e + kk] = (unsigned char)((old >> sh) & 0xFu); } }
        C1(s.x, d.x, 0) C1(s.y, d.y, 1) C1(s.z, d.z, 2) C1(s.w, d.w, 3)
#undef C1
    }
    __syncthreads();
    unsigned* dst = partial32 + (unsigned)blockIdx.x * (PSIZE / 4);
    for (int i = tid; i < PSIZE / 4; i += 512) dst[i] = bins[i];
}

// Fused reduce + scan1. Block g: nodes [g*1024, g*1024+1024), 4 nodes/thread.
// Chunk-walk addr of node n is simply n (p*PSIZE + (n-p*PSIZE)), so 4
// consecutive nodes = one u32 per chunk. Emits dinv, chunk-prefix bytes,
// block-local exclusive off, bsum[g].
__global__ __launch_bounds__(256) void redscan_kernel(unsigned* __restrict__ partial32,
                                                      float* __restrict__ dinv,
                                                      unsigned* __restrict__ off,
                                                      unsigned* __restrict__ bsum,
                                                      float* __restrict__ sums) {
    __shared__ unsigned s[256];
    const int tid = threadIdx.x;
    if (blockIdx.x == 0 && tid < 128) sums[tid] = 0.f;
    const int n0 = blockIdx.x * 1024 + tid * 4;
    unsigned cntk[4] = {0, 0, 0, 0};
    unsigned degk[4] = {0, 0, 0, 0};
    if (n0 < N_NODES) {   // n0+3 < N_NODES too (100000 % 4 == 0)
        unsigned idx = (unsigned)n0 >> 2;
#pragma unroll 8
        for (int c = 0; c < NCHUNK; ++c) {
            unsigned v = partial32[idx];
            unsigned nv = 0;
#pragma unroll
            for (int k = 0; k < 4; ++k) {
                unsigned byte = (v >> (k * 8)) & 0xFFu;
                nv |= (cntk[k] & 0xFFu) << (k * 8);   // exclusive prefix so far
                cntk[k] += byte >> 4;
                degk[k] += byte & 0xFu;
            }
            partial32[idx] = nv;
            idx += (NPART * PSIZE) / 4;
        }
#pragma unroll
        for (int k = 0; k < 4; ++k)
            dinv[n0 + k] = rsqrtf((float)(degk[k] + 1u));
    }
    unsigned tsum = cntk[0] + cntk[1] + cntk[2] + cntk[3];
    s[tid] = tsum;
    __syncthreads();
    for (int d = 1; d < 256; d <<= 1) {
        unsigned t = (tid >= d) ? s[tid - d] : 0u;
        __syncthreads();
        s[tid] += t;
        __syncthreads();
    }
    unsigned run = s[tid] - tsum;
    if (n0 < N_NODES) {
        uint4 o;
        o.x = run;
        o.y = run + cntk[0];
        o.z = o.y + cntk[1];
        o.w = o.z + cntk[2];
        *(uint4*)&off[n0] = o;
    }
    if (tid == 255) bsum[blockIdx.x] = s[255];
}

__global__ __launch_bounds__(128) void scan2_kernel(unsigned* __restrict__ bsum) {
    __shared__ unsigned s[128];
    const int tid = threadIdx.x;
    unsigned v = (tid < SCAN_NB) ? bsum[tid] : 0u;
    s[tid] = v;
    __syncthreads();
    for (int d = 1; d < 128; d <<= 1) {
        unsigned t = (tid >= d) ? s[tid - d] : 0u;
        __syncthreads();
        s[tid] += t;
        __syncthreads();
    }
    if (tid < SCAN_NB) bsum[tid] = s[tid] - v;
}

// Single-pass placement: slot = off[d] + bsum[d>>10] + chunk-prefix + rank.
// Payload = {src, raw edge weight} (no dinv gathers).
__global__ __launch_bounds__(256) void place_kernel(const int* __restrict__ s32,
                                                    const int* __restrict__ d32,
                                                    const float* __restrict__ ew,
                                                    const unsigned* __restrict__ off,
                                                    const unsigned* __restrict__ bsum,
                                                    const unsigned* __restrict__ partial32,
                                                    const unsigned char* __restrict__ rank,
                                                    int2* __restrict__ buck) {
    int i = blockIdx.x * 256 + threadIdx.x;   // int4 index over edges
    if (i >= N_EDGES / 4) return;
    int4 s = ((const int4*)s32)[i];
    int4 d = ((const int4*)d32)[i];
    float4 w = ((const float4*)ew)[i];
    uchar4 r = ((const uchar4*)rank)[i];
    const unsigned char* pb = (const unsigned char*)partial32;
    int e = i * 4;
    int b = e / CHUNK_E;   // e..e+3 in same chunk (CHUNK_E % 4 == 0)
    unsigned base = (unsigned)b * NPART * PSIZE;
#define P1(sk, dk, wk, rk) { \
    if ((unsigned)(sk) < N_NODES && (unsigned)(dk) < N_NODES) { \
        unsigned pref = pb[base + (unsigned)(dk)]; \
        unsigned slot = off[dk] + bsum[(unsigned)(dk) >> 10] + pref + (rk); \
        if (slot < N_EDGES) \
            buck[slot] = make_int2((sk), __float_as_int(wk)); } }
    P1(s.x, d.x, w.x, r.x) P1(s.y, d.y, w.y, r.y)
    P1(s.z, d.z, w.z, r.z) P1(s.w, d.w, w.w, r.w)
#undef P1
}

// h' = (x @ W^T) * dinv[row], stored bf16 via MFMA 16x16x32 (layout validated R6).
__global__ __launch_bounds__(256) void gemm_kernel(const float* __restrict__ x,
                                                   const float* __restrict__ W,
                                                   const float* __restrict__ dinv,
                                                   unsigned short* __restrict__ hb) {
    __shared__ short wlds[16 * 64 * 8];   // 16 KB
    const int tid = threadIdx.x;
    const int n0 = blockIdx.x * 64;
    {
        int out = tid & 63;
        int kb = tid >> 6;
#pragma unroll
        for (int i = 0; i < 4; ++i) {
            int koct = kb + i * 4;
            const float* wp = &W[out * F_IN + koct * 8];
            float4 aa = *(const float4*)wp;
            float4 bb = *(const float4*)(wp + 4);
            bf16x8 f;
            f[0] = (short)f2bf(aa.x); f[1] = (short)f2bf(aa.y);
            f[2] = (short)f2bf(aa.z); f[3] = (short)f2bf(aa.w);
            f[4] = (short)f2bf(bb.x); f[5] = (short)f2bf(bb.y);
            f[6] = (short)f2bf(bb.z); f[7] = (short)f2bf(bb.w);
            ((bf16x8*)wlds)[koct * 64 + out] = f;
        }
    }
    __syncthreads();
    const int wv = tid >> 6;
    const int lane = tid & 63;
    const int m = lane & 15;
    const int quad = lane >> 4;
    const int row = n0 + wv * 16 + m;
    const bool rv = row < N_NODES;
    const float* xrow = &x[(long)row * F_IN + quad * 8];
    f32x4 acc0 = {0.f, 0.f, 0.f, 0.f};
    f32x4 acc1 = {0.f, 0.f, 0.f, 0.f};
    f32x4 acc2 = {0.f, 0.f, 0.f, 0.f};
    f32x4 acc3 = {0.f, 0.f, 0.f, 0.f};
#pragma unroll
    for (int kc = 0; kc < 4; ++kc) {
        bf16x8 a = {0, 0, 0, 0, 0, 0, 0, 0};
        if (rv) {
            float4 aa = *(const float4*)(xrow + kc * 32);
            float4 bb = *(const float4*)(xrow + kc * 32 + 4);
            a[0] = (short)f2bf(aa.x); a[1] = (short)f2bf(aa.y);
            a[2] = (short)f2bf(aa.z); a[3] = (short)f2bf(aa.w);
            a[4] = (short)f2bf(bb.x); a[5] = (short)f2bf(bb.y);
            a[6] = (short)f2bf(bb.z); a[7] = (short)f2bf(bb.w);
        }
        const bf16x8* wrow = &((const bf16x8*)wlds)[(kc * 4 + quad) * 64 + m];
        acc0 = __builtin_amdgcn_mfma_f32_16x16x32_bf16(a, wrow[0],  acc0, 0, 0, 0);
        acc1 = __builtin_amdgcn_mfma_f32_16x16x32_bf16(a, wrow[16], acc1, 0, 0, 0);
        acc2 = __builtin_amdgcn_mfma_f32_16x16x32_bf16(a, wrow[32], acc2, 0, 0, 0);
        acc3 = __builtin_amdgcn_mfma_f32_16x16x32_bf16(a, wrow[48], acc3, 0, 0, 0);
    }
#pragma unroll
    for (int r = 0; r < 4; ++r) {
        int node = n0 + wv * 16 + quad * 4 + r;
        if (node < N_NODES) {
            float dv = dinv[node];
            unsigned short* hr = &hb[(long)node * F_OUT + m];
            hr[0]  = f2bf(acc0[r] * dv);
            hr[16] = f2bf(acc1[r] * dv);
            hr[32] = f2bf(acc2[r] * dv);
            hr[48] = f2bf(acc3[r] * dv);
        }
    }
}

// Wave-per-node aggregation: 64 lanes = 8 edge slots x 8 channel lanes (uint4
// h'-loads), unroll-2 -> 16 independent gather chains. out = relu(dinv_n *
// (sum h'[s]*w + h'[n])); BN sum/sumsq fused.
#define AGG_BLOCKS 2048
#define NPW 13   // ceil(100000 / 8192 waves)
__global__ __launch_bounds__(256) void aggregate_kernel(
    const unsigned short* __restrict__ hb, const float* __restrict__ dinv,
    const unsigned* __restrict__ off, const unsigned* __restrict__ bsum,
    const int2* __restrict__ buck, float* __restrict__ out,
    float* __restrict__ sums) {
    const int tid = threadIdx.x;
    const int wv = tid >> 6;
    const int lane = tid & 63;
    const int es = lane >> 3;     // edge slot 0..7
    const int cl = lane & 7;      // channel group: 8 channels = 16 B bf16
    float s1[8] = {0.f, 0.f, 0.f, 0.f, 0.f, 0.f, 0.f, 0.f};
    float s2[8] = {0.f, 0.f, 0.f, 0.f, 0.f, 0.f, 0.f, 0.f};

    const int wid = blockIdx.x * 4 + wv;
    const int nbeg = wid * NPW;
    const int nend = (nbeg + NPW < N_NODES) ? nbeg + NPW : N_NODES;
    for (int n = nbeg; n < nend; ++n) {
        const unsigned o = off[n] + bsum[(unsigned)n >> 10];
        const unsigned onext = (n + 1 < N_NODES)
            ? off[n + 1] + bsum[(unsigned)(n + 1) >> 10]
            : (unsigned)N_EDGES;   // careful: last node ends at total edges kept
        const unsigned c = onext - o;
        float a0[8] = {0.f, 0.f, 0.f, 0.f, 0.f, 0.f, 0.f, 0.f};
        float a1[8] = {0.f, 0.f, 0.f, 0.f, 0.f, 0.f, 0.f, 0.f};
        unsigned j = es;
        for (; j + 8 < c; j += 16) {
            int2 b1 = buck[o + j];
            int2 b2 = buck[o + j + 8];
            uint4 p1 = *(const uint4*)(hb + ((long)b1.x << 6) + cl * 8);
            uint4 p2 = *(const uint4*)(hb + ((long)b2.x << 6) + cl * 8);
            float w1 = __int_as_float(b1.y);
            float w2 = __int_as_float(b2.y);
            a0[0] += bfl((unsigned short)p1.x) * w1;
            a0[1] += bfl((unsigned short)(p1.x >> 16)) * w1;
            a0[2] += bfl((unsigned short)p1.y) * w1;
            a0[3] += bfl((unsigned short)(p1.y >> 16)) * w1;
            a0[4] += bfl((unsigned short)p1.z) * w1;
            a0[5] += bfl((unsigned short)(p1.z >> 16)) * w1;
            a0[6] += bfl((unsigned short)p1.w) * w1;
            a0[7] += bfl((unsigned short)(p1.w >> 16)) * w1;
            a1[0] += bfl((unsigned short)p2.x) * w2;
            a1[1] += bfl((unsigned short)(p2.x >> 16)) * w2;
            a1[2] += bfl((unsigned short)p2.y) * w2;
            a1[3] += bfl((unsigned short)(p2.y >> 16)) * w2;
            a1[4] += bfl((unsigned short)p2.z) * w2;
            a1[5] += bfl((unsigned short)(p2.z >> 16)) * w2;
            a1[6] += bfl((unsigned short)p2.w) * w2;
            a1[7] += bfl((unsigned short)(p2.w >> 16)) * w2;
        }
        if (j < c) {
            int2 b1 = buck[o + j];
            uint4 p1 = *(const uint4*)(hb + ((long)b1.x << 6) + cl * 8);
            float w1 = __int_as_float(b1.y);
            a0[0] += bfl((unsigned short)p1.x) * w1;
            a0[1] += bfl((unsigned short)(p1.x >> 16)) * w1;
            a0[2] += bfl((unsigned short)p1.y) * w1;
            a0[3] += bfl((unsigned short)(p1.y >> 16)) * w1;
            a0[4] += bfl((unsigned short)p1.z) * w1;
            a0[5] += bfl((unsigned short)(p1.z >> 16)) * w1;
            a0[6] += bfl((unsigned short)p1.w) * w1;
            a0[7] += bfl((unsigned short)(p1.w >> 16)) * w1;
        }
#pragma unroll
        for (int k = 0; k < 8; ++k) {
            a0[k] += a1[k];
            a0[k] += __shfl_xor(a0[k], 8);
            a0[k] += __shfl_xor(a0[k], 16);
            a0[k] += __shfl_xor(a0[k], 32);
        }
        if (es == 0) {
            float dn = dinv[n];
            uint4 pn = *(const uint4*)(hb + ((long)n << 6) + cl * 8);
            float hn[8] = {bfl((unsigned short)pn.x), bfl((unsigned short)(pn.x >> 16)),
                           bfl((unsigned short)pn.y), bfl((unsigned short)(pn.y >> 16)),
                           bfl((unsigned short)pn.z), bfl((unsigned short)(pn.z >> 16)),
                           bfl((unsigned short)pn.w), bfl((unsigned short)(pn.w >> 16))};
            float4 o0, o1;
            float* op = &o0.x;
#pragma unroll
            for (int k = 0; k < 8; ++k) {
                float v = fmaxf(dn * (a0[k] + hn[k]), 0.f);
                ((k < 4) ? (&o0.x) : (&o1.x))[k & 3] = v;
                s1[k] += v;
                s2[k] += v * v;
            }
            (void)op;
            float* orow = &out[(long)n * F_OUT + cl * 8];
            *(float4*)orow = o0;
            *(float4*)(orow + 4) = o1;
        }
    }
    __shared__ float l1[256];   // [wave][64 ch]
    __shared__ float l2[256];
    if (es == 0) {
#pragma unroll
        for (int k = 0; k < 8; ++k) {
            l1[wv * 64 + cl * 8 + k] = s1[k];
            l2[wv * 64 + cl * 8 + k] = s2[k];
        }
    }
    __syncthreads();
    if (tid < 64) {
        float b1 = l1[tid] + l1[64 + tid] + l1[128 + tid] + l1[192 + tid];
        float b2 = l2[tid] + l2[64 + tid] + l2[128 + tid] + l2[192 + tid];
        atomicAdd(&sums[tid], b1);
        atomicAdd(&sums[64 + tid], b2);
    }
}

// BN apply with inline finalize: scale/bias computed once per block in LDS.
__global__ __launch_bounds__(256) void apply_kernel(float* __restrict__ agg,
                                                    const float* __restrict__ sums,
                                                    const float* __restrict__ gamma,
                                                    const float* __restrict__ beta) {
    __shared__ float sc[64], bi[64];
    if (threadIdx.x < 64) {
        int c = threadIdx.x;
        const float inv_n = 1.0f / (float)N_NODES;
        float mean = sums[c] * inv_n;
        float var = sums[64 + c] * inv_n - mean * mean;
        float rs = rsqrtf(var + BN_EPS);
        float scale = rs * gamma[c];
        sc[c] = scale;
        bi[c] = beta[c] - mean * scale;
    }
    __syncthreads();
    int i = blockIdx.x * blockDim.x + threadIdx.x;
    if (i >= N_NODES * 16) return;
    int c4 = (i & 15) << 2;
    float4 v = ((float4*)agg)[i];
    v.x = v.x * sc[c4 + 0] + bi[c4 + 0];
    v.y = v.y * sc[c4 + 1] + bi[c4 + 1];
    v.z = v.z * sc[c4 + 2] + bi[c4 + 2];
    v.w = v.w * sc[c4 + 3] + bi[c4 + 3];
    ((float4*)agg)[i] = v;
}

extern "C" void kernel_launch(void* const* d_in, const int* in_sizes, int n_in,
                              void* d_out, int out_size, void* d_ws, size_t ws_size,
                              hipStream_t stream) {
    const float* x     = (const float*)d_in[0];
    const void*  ei    = d_in[1];
    const float* ew    = (const float*)d_in[2];
    const float* W     = (const float*)d_in[3];
    const float* gamma = (const float*)d_in[4];
    const float* beta  = (const float*)d_in[5];
    float* out = (float*)d_out;
    float* ws  = (float*)d_ws;

    int*            s32       = (int*)ws;
    int*            d32       = (int*)(ws + 1600000);
    unsigned*       partial32 = (unsigned*)(ws + 3200000);
    unsigned short* hb        = (unsigned short*)(ws + 3200000);  // aliases partial
    int2*           buck      = (int2*)(ws + 6400000);
    float*          dinv      = ws + 9600000;
    float*          sums      = ws + 9700000;
    unsigned*       off       = (unsigned*)(ws + 9800128);
    unsigned*       bsum      = (unsigned*)(ws + 9900128);
    unsigned char*  rank      = (unsigned char*)d_out;   // first 1.6 MB of out, pre-aggregate

    convert_kernel<<<(N_EDGES / 4 + 255) / 256, 256, 0, stream>>>(ei, s32, d32);
    count_kernel<<<NPART * NCHUNK, 512, 0, stream>>>(s32, d32, partial32, rank);
    redscan_kernel<<<SCAN_NB, 256, 0, stream>>>(partial32, dinv, off, bsum, sums);
    scan2_kernel<<<1, 128, 0, stream>>>(bsum);
    place_kernel<<<(N_EDGES / 4 + 255) / 256, 256, 0, stream>>>(s32, d32, ew, off, bsum,
                                                                partial32, rank, buck);
    gemm_kernel<<<(N_NODES + 63) / 64, 256, 0, stream>>>(x, W, dinv, hb);  // overwrites partial
    aggregate_kernel<<<AGG_BLOCKS, 256, 0, stream>>>(hb, dinv, off, bsum, buck, out, sums);
    apply_kernel<<<(N_NODES * 16 + 255) / 256, 256, 0, stream>>>(out, sums, gamma, beta);
}

// Round 10
// 291.387 us; speedup vs baseline: 1.0460x; 1.0460x over previous
//
#include <hip/hip_runtime.h>

#define N_NODES 100000
#define N_EDGES 1600000
#define F_IN 128
#define F_OUT 64
#define BN_EPS 1e-5f

#define NPART 2            // node partitions (p = d >= PSIZE)
#define NCHUNK 128         // edge chunks
#define PSIZE 50000        // nodes per partition
#define CHUNK_E 12500      // edges per chunk

#define SCAN_NB 98         // ceil(100000/1024) scan blocks

// ---------------- workspace layout (4-byte elements) ----------------
// s32    : [0,        1600000)   edge sources, int32 (written by count pass p=0)
// d32    : [1600000,  3200000)   edge dests | rank<<27 (written by owning pass)
// partial: [3200000,  6400000)   byte per (chunk, node): deg-nibble|cnt-nibble,
//                                then u8 cnt-prefix; hb (bf16 h') aliases after place
// buck   : [6400000,  9600000)   int2 {src, ew-bits} per edge
// dinv   : [9600000,  9700000)
// sums   : [9700000,  9700128)
// off    : [9800128,  9900128)   block-local exclusive prefix (add bsum[n>>10])
// bsum   : [9900128,  9900256)

typedef __attribute__((ext_vector_type(8))) short bf16x8;
typedef __attribute__((ext_vector_type(4))) float f32x4;

__device__ __forceinline__ unsigned short f2bf(float x) {
    unsigned u = __float_as_uint(x);
    u += 0x7fffu + ((u >> 16) & 1u);   // RTNE
    return (unsigned short)(u >> 16);
}
__device__ __forceinline__ float4 bf4(uint2 p) {
    return make_float4(__int_as_float((int)(p.x << 16)),
                       __int_as_float((int)(p.x & 0xffff0000u)),
                       __int_as_float((int)(p.y << 16)),
                       __int_as_float((int)(p.y & 0xffff0000u)));
}

// Fused convert+count. Block (p,b): nibble-packed histogram of chunk b for
// partition p (LDS byte: deg lo-nibble | cnt hi-nibble). Pass p=0 writes s32.
// The owning pass (dst in partition p) writes d32[e] = d | rank<<27, where
// rank = within-(chunk,dst) order from the LDS atomicAdd return value.
__global__ __launch_bounds__(512) void count_kernel(const void* __restrict__ ei,
                                                    int* __restrict__ s32,
                                                    int* __restrict__ d32,
                                                    unsigned* __restrict__ partial32) {
    __shared__ unsigned bins[PSIZE / 4];   // 50 KB
    const long long* q = (const long long*)ei;
    long long probe = q[threadIdx.x & 63];
    bool badp = (probe < 0 || probe >= N_NODES);
    int is64 = (__ballot(badp) == 0ULL);   // block-uniform

    const int tid = threadIdx.x;
    const int p = blockIdx.x % NPART;
    const int b = blockIdx.x / NPART;
    const int p0 = p * PSIZE;
    for (int i = tid; i < PSIZE / 4; i += 512) bins[i] = 0u;
    __syncthreads();
    const int e0 = b * CHUNK_E;
    for (int i = tid; i < CHUNK_E / 4; i += 512) {
        int e = e0 + i * 4;
        int4 s, d;
        if (is64) {
            longlong2 a = *(const longlong2*)&q[e];
            longlong2 bb = *(const longlong2*)&q[e + 2];
            s = make_int4((int)a.x, (int)a.y, (int)bb.x, (int)bb.y);
            longlong2 c2 = *(const longlong2*)&q[N_EDGES + e];
            longlong2 e2 = *(const longlong2*)&q[N_EDGES + e + 2];
            d = make_int4((int)c2.x, (int)c2.y, (int)e2.x, (int)e2.y);
        } else {
            s = ((const int4*)ei)[e >> 2];
            d = ((const int4*)ei)[(N_EDGES >> 2) + (e >> 2)];
        }
        if (p == 0) ((int4*)s32)[e >> 2] = s;
#define C1(sk, dk, kk) { \
        unsigned si = (unsigned)((sk) - p0); \
        if (si < PSIZE) atomicAdd(&bins[si >> 2], 1u << ((si & 3) * 8)); \
        unsigned dd = (unsigned)((dk) - p0); \
        if ((unsigned)(sk) < N_NODES && dd < PSIZE) { \
            unsigned sh = (dd & 3) * 8 + 4; \
            unsigned old = atomicAdd(&bins[dd >> 2], 16u << ((dd & 3) * 8)); \
            d32[e + kk] = (dk) | (int)(((old >> sh) & 0xFu) << 27); } }
        C1(s.x, d.x, 0) C1(s.y, d.y, 1) C1(s.z, d.z, 2) C1(s.w, d.w, 3)
#undef C1
    }
    __syncthreads();
    unsigned* dst = partial32 + (unsigned)blockIdx.x * (PSIZE / 4);
    for (int i = tid; i < PSIZE / 4; i += 512) dst[i] = bins[i];
}

// Fused reduce + scan1 (validated R9). Emits dinv, chunk-prefix bytes,
// block-local exclusive off, bsum[g].
__global__ __launch_bounds__(256) void redscan_kernel(unsigned* __restrict__ partial32,
                                                      float* __restrict__ dinv,
                                                      unsigned* __restrict__ off,
                                                      unsigned* __restrict__ bsum,
                                                      float* __restrict__ sums) {
    __shared__ unsigned s[256];
    const int tid = threadIdx.x;
    if (blockIdx.x == 0 && tid < 128) sums[tid] = 0.f;
    const int n0 = blockIdx.x * 1024 + tid * 4;
    unsigned cntk[4] = {0, 0, 0, 0};
    unsigned degk[4] = {0, 0, 0, 0};
    if (n0 < N_NODES) {
        unsigned idx = (unsigned)n0 >> 2;
#pragma unroll 8
        for (int c = 0; c < NCHUNK; ++c) {
            unsigned v = partial32[idx];
            unsigned nv = 0;
#pragma unroll
            for (int k = 0; k < 4; ++k) {
                unsigned byte = (v >> (k * 8)) & 0xFFu;
                nv |= (cntk[k] & 0xFFu) << (k * 8);
                cntk[k] += byte >> 4;
                degk[k] += byte & 0xFu;
            }
            partial32[idx] = nv;
            idx += (NPART * PSIZE) / 4;
        }
#pragma unroll
        for (int k = 0; k < 4; ++k)
            dinv[n0 + k] = rsqrtf((float)(degk[k] + 1u));
    }
    unsigned tsum = cntk[0] + cntk[1] + cntk[2] + cntk[3];
    s[tid] = tsum;
    __syncthreads();
    for (int d = 1; d < 256; d <<= 1) {
        unsigned t = (tid >= d) ? s[tid - d] : 0u;
        __syncthreads();
        s[tid] += t;
        __syncthreads();
    }
    unsigned run = s[tid] - tsum;
    if (n0 < N_NODES) {
        uint4 o;
        o.x = run;
        o.y = run + cntk[0];
        o.z = o.y + cntk[1];
        o.w = o.z + cntk[2];
        *(uint4*)&off[n0] = o;
    }
    if (tid == 255) bsum[blockIdx.x] = s[255];
}

__global__ __launch_bounds__(128) void scan2_kernel(unsigned* __restrict__ bsum) {
    __shared__ unsigned s[128];
    const int tid = threadIdx.x;
    unsigned v = (tid < SCAN_NB) ? bsum[tid] : 0u;
    s[tid] = v;
    __syncthreads();
    for (int d = 1; d < 128; d <<= 1) {
        unsigned t = (tid >= d) ? s[tid - d] : 0u;
        __syncthreads();
        s[tid] += t;
        __syncthreads();
    }
    if (tid < SCAN_NB) bsum[tid] = s[tid] - v;
}

// Single-pass placement: slot = off[d] + bsum[d>>10] + chunk-prefix + rank,
// rank unpacked from d32 bits 27-30. Payload = {src, raw edge weight}.
__global__ __launch_bounds__(256) void place_kernel(const int* __restrict__ s32,
                                                    const int* __restrict__ d32,
                                                    const float* __restrict__ ew,
                                                    const unsigned* __restrict__ off,
                                                    const unsigned* __restrict__ bsum,
                                                    const unsigned* __restrict__ partial32,
                                                    int2* __restrict__ buck) {
    int i = blockIdx.x * 256 + threadIdx.x;   // int4 index over edges
    if (i >= N_EDGES / 4) return;
    int4 s = ((const int4*)s32)[i];
    int4 d = ((const int4*)d32)[i];
    float4 w = ((const float4*)ew)[i];
    const unsigned char* pb = (const unsigned char*)partial32;
    int e = i * 4;
    int b = e / CHUNK_E;   // e..e+3 in same chunk (CHUNK_E % 4 == 0)
    unsigned base = (unsigned)b * NPART * PSIZE;
#define P1(sk, dvk, wk) { \
    unsigned dd = (unsigned)(dvk) & 0x07FFFFFFu; \
    unsigned rk = ((unsigned)(dvk)) >> 27; \
    if ((unsigned)(sk) < N_NODES && dd < N_NODES) { \
        unsigned pref = pb[base + dd]; \
        unsigned slot = off[dd] + bsum[dd >> 10] + pref + rk; \
        if (slot < N_EDGES) \
            buck[slot] = make_int2((sk), __float_as_int(wk)); } }
    P1(s.x, d.x, w.x) P1(s.y, d.y, w.y) P1(s.z, d.z, w.z) P1(s.w, d.w, w.w)
#undef P1
}

// h' = (x @ W^T) * dinv[row], stored bf16 via MFMA 16x16x32 (validated R6/R9).
__global__ __launch_bounds__(256) void gemm_kernel(const float* __restrict__ x,
                                                   const float* __restrict__ W,
                                                   const float* __restrict__ dinv,
                                                   unsigned short* __restrict__ hb) {
    __shared__ short wlds[16 * 64 * 8];   // 16 KB
    const int tid = threadIdx.x;
    const int n0 = blockIdx.x * 64;
    {
        int out = tid & 63;
        int kb = tid >> 6;
#pragma unroll
        for (int i = 0; i < 4; ++i) {
            int koct = kb + i * 4;
            const float* wp = &W[out * F_IN + koct * 8];
            float4 aa = *(const float4*)wp;
            float4 bb = *(const float4*)(wp + 4);
            bf16x8 f;
            f[0] = (short)f2bf(aa.x); f[1] = (short)f2bf(aa.y);
            f[2] = (short)f2bf(aa.z); f[3] = (short)f2bf(aa.w);
            f[4] = (short)f2bf(bb.x); f[5] = (short)f2bf(bb.y);
            f[6] = (short)f2bf(bb.z); f[7] = (short)f2bf(bb.w);
            ((bf16x8*)wlds)[koct * 64 + out] = f;
        }
    }
    __syncthreads();
    const int wv = tid >> 6;
    const int lane = tid & 63;
    const int m = lane & 15;
    const int quad = lane >> 4;
    const int row = n0 + wv * 16 + m;
    const bool rv = row < N_NODES;
    const float* xrow = &x[(long)row * F_IN + quad * 8];
    f32x4 acc0 = {0.f, 0.f, 0.f, 0.f};
    f32x4 acc1 = {0.f, 0.f, 0.f, 0.f};
    f32x4 acc2 = {0.f, 0.f, 0.f, 0.f};
    f32x4 acc3 = {0.f, 0.f, 0.f, 0.f};
#pragma unroll
    for (int kc = 0; kc < 4; ++kc) {
        bf16x8 a = {0, 0, 0, 0, 0, 0, 0, 0};
        if (rv) {
            float4 aa = *(const float4*)(xrow + kc * 32);
            float4 bb = *(const float4*)(xrow + kc * 32 + 4);
            a[0] = (short)f2bf(aa.x); a[1] = (short)f2bf(aa.y);
            a[2] = (short)f2bf(aa.z); a[3] = (short)f2bf(aa.w);
            a[4] = (short)f2bf(bb.x); a[5] = (short)f2bf(bb.y);
            a[6] = (short)f2bf(bb.z); a[7] = (short)f2bf(bb.w);
        }
        const bf16x8* wrow = &((const bf16x8*)wlds)[(kc * 4 + quad) * 64 + m];
        acc0 = __builtin_amdgcn_mfma_f32_16x16x32_bf16(a, wrow[0],  acc0, 0, 0, 0);
        acc1 = __builtin_amdgcn_mfma_f32_16x16x32_bf16(a, wrow[16], acc1, 0, 0, 0);
        acc2 = __builtin_amdgcn_mfma_f32_16x16x32_bf16(a, wrow[32], acc2, 0, 0, 0);
        acc3 = __builtin_amdgcn_mfma_f32_16x16x32_bf16(a, wrow[48], acc3, 0, 0, 0);
    }
#pragma unroll
    for (int r = 0; r < 4; ++r) {
        int node = n0 + wv * 16 + quad * 4 + r;
        if (node < N_NODES) {
            float dv = dinv[node];
            unsigned short* hr = &hb[(long)node * F_OUT + m];
            hr[0]  = f2bf(acc0[r] * dv);
            hr[16] = f2bf(acc1[r] * dv);
            hr[32] = f2bf(acc2[r] * dv);
            hr[48] = f2bf(acc3[r] * dv);
        }
    }
}

// Wave-per-node aggregation — R8 validated shape: 64 lanes = 4 edge slots x 16
// channel lanes, uint2 h'-loads, unroll-2 (8 gather chains). Contiguous
// 13-node run per wave. out = relu(dinv_n * (sum h'[s]*w + h'[n])); BN fused.
#define AGG_BLOCKS 2048
#define NPW 13   // ceil(100000 / 8192 waves)
__global__ __launch_bounds__(256) void aggregate_kernel(
    const unsigned short* __restrict__ hb, const float* __restrict__ dinv,
    const unsigned* __restrict__ off, const unsigned* __restrict__ bsum,
    const int2* __restrict__ buck, float* __restrict__ out,
    float* __restrict__ sums) {
    const int tid = threadIdx.x;
    const int wv = tid >> 6;
    const int lane = tid & 63;
    const int es = lane >> 4;
    const int cl = lane & 15;
    float s1[4] = {0.f, 0.f, 0.f, 0.f};
    float s2[4] = {0.f, 0.f, 0.f, 0.f};

    const int wid = blockIdx.x * 4 + wv;
    const int nbeg = wid * NPW;
    const int nend = (nbeg + NPW < N_NODES) ? nbeg + NPW : N_NODES;
    for (int n = nbeg; n < nend; ++n) {
        const unsigned o = off[n] + bsum[(unsigned)n >> 10];
        const unsigned onext = (n + 1 < N_NODES)
            ? off[n + 1] + bsum[(unsigned)(n + 1) >> 10]
            : (unsigned)N_EDGES;   // all edges valid -> total kept == N_EDGES
        const unsigned c = onext - o;
        float4 a0 = make_float4(0.f, 0.f, 0.f, 0.f);
        float4 a1 = make_float4(0.f, 0.f, 0.f, 0.f);
        unsigned j = es;
        for (; j + 4 < c; j += 8) {
            int2 b1 = buck[o + j];
            int2 b2 = buck[o + j + 4];
            float4 h1 = bf4(((const uint2*)(hb + ((long)b1.x << 6)))[cl]);
            float4 h2 = bf4(((const uint2*)(hb + ((long)b2.x << 6)))[cl]);
            float w1 = __int_as_float(b1.y);
            float w2 = __int_as_float(b2.y);
            a0.x += h1.x * w1; a0.y += h1.y * w1; a0.z += h1.z * w1; a0.w += h1.w * w1;
            a1.x += h2.x * w2; a1.y += h2.y * w2; a1.z += h2.z * w2; a1.w += h2.w * w2;
        }
        if (j < c) {
            int2 bb = buck[o + j];
            float w = __int_as_float(bb.y);
            float4 hv = bf4(((const uint2*)(hb + ((long)bb.x << 6)))[cl]);
            a0.x += hv.x * w; a0.y += hv.y * w; a0.z += hv.z * w; a0.w += hv.w * w;
        }
        a0.x += a1.x; a0.y += a1.y; a0.z += a1.z; a0.w += a1.w;
        a0.x += __shfl_xor(a0.x, 16); a0.y += __shfl_xor(a0.y, 16);
        a0.z += __shfl_xor(a0.z, 16); a0.w += __shfl_xor(a0.w, 16);
        a0.x += __shfl_xor(a0.x, 32); a0.y += __shfl_xor(a0.y, 32);
        a0.z += __shfl_xor(a0.z, 32); a0.w += __shfl_xor(a0.w, 32);
        if (es == 0) {
            float dn = dinv[n];
            float4 hn = bf4(((const uint2*)(hb + ((long)n << 6)))[cl]);
            a0.x = fmaxf(dn * (a0.x + hn.x), 0.f);
            a0.y = fmaxf(dn * (a0.y + hn.y), 0.f);
            a0.z = fmaxf(dn * (a0.z + hn.z), 0.f);
            a0.w = fmaxf(dn * (a0.w + hn.w), 0.f);
            *(float4*)&out[(long)n * F_OUT + cl * 4] = a0;
            s1[0] += a0.x; s1[1] += a0.y; s1[2] += a0.z; s1[3] += a0.w;
            s2[0] += a0.x * a0.x; s2[1] += a0.y * a0.y;
            s2[2] += a0.z * a0.z; s2[3] += a0.w * a0.w;
        }
    }
    __shared__ float l1[256];
    __shared__ float l2[256];
    if (es == 0) {
#pragma unroll
        for (int k = 0; k < 4; ++k) {
            l1[wv * 64 + cl * 4 + k] = s1[k];
            l2[wv * 64 + cl * 4 + k] = s2[k];
        }
    }
    __syncthreads();
    if (tid < 64) {
        float b1 = l1[tid] + l1[64 + tid] + l1[128 + tid] + l1[192 + tid];
        float b2 = l2[tid] + l2[64 + tid] + l2[128 + tid] + l2[192 + tid];
        atomicAdd(&sums[tid], b1);
        atomicAdd(&sums[64 + tid], b2);
    }
}

// BN apply with inline finalize (validated R9).
__global__ __launch_bounds__(256) void apply_kernel(float* __restrict__ agg,
                                                    const float* __restrict__ sums,
                                                    const float* __restrict__ gamma,
                                                    const float* __restrict__ beta) {
    __shared__ float sc[64], bi[64];
    if (threadIdx.x < 64) {
        int c = threadIdx.x;
        const float inv_n = 1.0f / (float)N_NODES;
        float mean = sums[c] * inv_n;
        float var = sums[64 + c] * inv_n - mean * mean;
        float rs = rsqrtf(var + BN_EPS);
        float scale = rs * gamma[c];
        sc[c] = scale;
        bi[c] = beta[c] - mean * scale;
    }
    __syncthreads();
    int i = blockIdx.x * blockDim.x + threadIdx.x;
    if (i >= N_NODES * 16) return;
    int c4 = (i & 15) << 2;
    float4 v = ((float4*)agg)[i];
    v.x = v.x * sc[c4 + 0] + bi[c4 + 0];
    v.y = v.y * sc[c4 + 1] + bi[c4 + 1];
    v.z = v.z * sc[c4 + 2] + bi[c4 + 2];
    v.w = v.w * sc[c4 + 3] + bi[c4 + 3];
    ((float4*)agg)[i] = v;
}

extern "C" void kernel_launch(void* const* d_in, const int* in_sizes, int n_in,
                              void* d_out, int out_size, void* d_ws, size_t ws_size,
                              hipStream_t stream) {
    const float* x     = (const float*)d_in[0];
    const void*  ei    = d_in[1];
    const float* ew    = (const float*)d_in[2];
    const float* W     = (const float*)d_in[3];
    const float* gamma = (const float*)d_in[4];
    const float* beta  = (const float*)d_in[5];
    float* out = (float*)d_out;
    float* ws  = (float*)d_ws;

    int*            s32       = (int*)ws;
    int*            d32       = (int*)(ws + 1600000);
    unsigned*       partial32 = (unsigned*)(ws + 3200000);
    unsigned short* hb        = (unsigned short*)(ws + 3200000);  // aliases partial
    int2*           buck      = (int2*)(ws + 6400000);
    float*          dinv      = ws + 9600000;
    float*          sums      = ws + 9700000;
    unsigned*       off       = (unsigned*)(ws + 9800128);
    unsigned*       bsum      = (unsigned*)(ws + 9900128);

    count_kernel<<<NPART * NCHUNK, 512, 0, stream>>>(ei, s32, d32, partial32);
    redscan_kernel<<<SCAN_NB, 256, 0, stream>>>(partial32, dinv, off, bsum, sums);
    scan2_kernel<<<1, 128, 0, stream>>>(bsum);
    place_kernel<<<(N_EDGES / 4 + 255) / 256, 256, 0, stream>>>(s32, d32, ew, off, bsum,
                                                                partial32, buck);
    gemm_kernel<<<(N_NODES + 63) / 64, 256, 0, stream>>>(x, W, dinv, hb);  // overwrites partial
    aggregate_kernel<<<AGG_BLOCKS, 256, 0, stream>>>(hb, dinv, off, bsum, buck, out, sums);
    apply_kernel<<<(N_NODES * 16 + 255) / 256, 256, 0, stream>>>(out, sums, gamma, beta);
}